// Round 8
// baseline (162.509 us; speedup 1.0000x reference)
//
#include <hip/hip_runtime.h>

#define NSENT 64
#define NCAND 8192
#define LMAX  512
#define KOUT  128
#define TPB   512
#define CHUNK 1024
#define NCHUNK (NCAND / CHUNK)   // 8
#define NWIN   (NCAND / TPB)     // 16
#define SLOTS  (TPB / 64)        // 8

#if defined(__has_builtin)
#if __has_builtin(__builtin_amdgcn_readlane)
#define READLANE(v, l) __builtin_amdgcn_readlane((unsigned)(v), (unsigned)(l))
#endif
#endif
#ifndef READLANE
#define READLANE(v, l) ((unsigned)__shfl((int)(v), (int)(l)))
#endif

// ---------------------------------------------------------------------------
// Kernel A (unchanged from R7): 512 blocks (sentence = bid>>3, chunk = bid&7).
// Bitonic-sort 1024 u64 keys in LDS, write sorted chunk to ws.
// Key: high 32 = descending-orderable score bits, low 31 = (idx<<18)|(st<<9)|en
// ---------------------------------------------------------------------------
__global__ __launch_bounds__(TPB) void sort_chunks_kernel(
    const float* __restrict__ scores,
    const int*   __restrict__ starts,
    const int*   __restrict__ ends,
    unsigned long long* __restrict__ ws)
{
    __shared__ unsigned long long lk[CHUNK];
    const int  bid   = blockIdx.x;
    const int  sent  = bid >> 3;
    const int  chunk = bid & 7;
    const int  tid   = threadIdx.x;
    const long gbase = (long)sent * NCAND + (long)chunk * CHUNK;

    for (int i = tid; i < CHUNK; i += TPB) {
        unsigned u  = __float_as_uint(scores[gbase + i]);
        unsigned o  = (u & 0x80000000u) ? ~u : (u | 0x80000000u); // asc-orderable
        unsigned d  = ~o;                                          // descending
        unsigned st = (unsigned)starts[gbase + i];
        unsigned en = (unsigned)ends[gbase + i];
        unsigned gi = (unsigned)(chunk * CHUNK + i);               // idx in sentence
        lk[i] = ((unsigned long long)d << 32) | (gi << 18) | (st << 9) | en;
    }

    for (int k = 2; k <= CHUNK; k <<= 1) {
        for (int j = k >> 1; j > 0; j >>= 1) {
            __syncthreads();
            const int p   = tid;               // CHUNK/2 == TPB: one CX per thread
            const int low = p & (j - 1);
            const int i   = ((p - low) << 1) | low;
            const int q   = i | j;
            unsigned long long a = lk[i];
            unsigned long long b = lk[q];
            bool up = ((i & k) == 0);
            if ((a > b) == up) { lk[i] = b; lk[q] = a; }
        }
    }
    __syncthreads();

    unsigned long long* wo = ws + (long)bid * CHUNK;
    for (int i = tid; i < CHUNK; i += TPB) wo[i] = lk[i];
}

// ---------------------------------------------------------------------------
// Kernel B: 64 blocks (one per sentence).
//  1. load 8 sorted chunks, merge-path merge in 3 stages (512 threads)
//  2. greedy non-crossing selection ENTIRELY in wave 0, ZERO block barriers:
//     - per 512-window: lane-major b128 payload reads + O(1) sparse-table
//       crossing filter (4 LDS reads/candidate, all independent)
//     - serial pop loop: 1 ballot + readlane per accept; incremental table
//       update by 62-lane LDS-atomic burst; branch-free register retest
//  3. parallel rank-sort of the <=128 selected by (start,end) (512 threads)
// ---------------------------------------------------------------------------
__global__ __launch_bounds__(TPB) void merge_greedy_kernel(
    const unsigned long long* __restrict__ ws,
    int* __restrict__ out)
{
    __shared__ __align__(16) unsigned long long keys[NCAND];  // 64 KiB
    // TT1[k][i] = max s2e over [i, i+2^k) ; TT2[k][i] = min e2s over [i, i+2^k)
    __shared__ int TT1[5][LMAX];              // 10 KiB
    __shared__ int TT2[5][LMAX];              // 10 KiB
    __shared__ unsigned acc_list[KOUT];
    __shared__ int      n_sh;
    __shared__ unsigned mkbuf[KOUT];
    __shared__ unsigned paybuf[KOUT];
    __shared__ int      cnt[KOUT * 4];

    const int sent = blockIdx.x;
    const int tid  = threadIdx.x;
    const unsigned long long* wi = ws + (long)sent * NCAND;

    // init tables (5 levels each)
    for (int i = tid; i < 5 * LMAX; i += TPB) {
        (&TT1[0][0])[i] = -1;
        (&TT2[0][0])[i] = LMAX;
    }

    // load keys as 16B packets
    {
        const ulonglong2* wi2 = (const ulonglong2*)wi;
        ulonglong2* k2 = (ulonglong2*)keys;
        for (int i = tid; i < NCAND / 2; i += TPB) k2[i] = wi2[i];
    }
    __syncthreads();

    // ---- merge: 8 sorted runs of 1024 -> 1 run of 8192 (3 stages) ----------
    #pragma unroll
    for (int stg = 0; stg < 3; ++stg) {
        const int Lh  = CHUNK << stg;          // 1024, 2048, 4096
        const int tpp = Lh >> 3;               // threads per pair
        const int pair = tid / tpp;
        const int o    = (tid % tpp) * 16;
        const unsigned long long* A = keys + pair * (Lh * 2);
        const unsigned long long* B = A + Lh;
        int lo = (o > Lh) ? o - Lh : 0;
        int hi = (o < Lh) ? o : Lh;
        while (lo < hi) {                      // smallest i : A[i] > B[o-1-i]
            int mid = (lo + hi) >> 1;
            if (A[mid] <= B[o - 1 - mid]) lo = mid + 1; else hi = mid;
        }
        int i = lo, j = o - lo;
        unsigned long long r[16];
        #pragma unroll
        for (int x = 0; x < 16; ++x) {
            bool ta = (j >= Lh) || (i < Lh && A[i] <= B[j]);
            r[x] = ta ? A[i++] : B[j++];
        }
        __syncthreads();                       // all reads done before overwrite
        unsigned long long* O = keys + pair * (Lh * 2) + o;
        #pragma unroll
        for (int x = 0; x < 16; ++x) O[x] = r[x];
        __syncthreads();
    }
    // (last merge stage ends with __syncthreads: keys + TT init visible)

    // ---- greedy: wave 0 only, no block barriers -----------------------------
    if (tid < 64) {
        const int lane = tid;
        // incremental-update role: accepted (sst,sen) bumps TT1[k][i] for
        // i in [sst-2^k+1, sst], all 5 levels = 31 cells; TT2 likewise.
        const int sidel = (lane < 31) ? lane : (lane - 31);
        const int k_m   = 31 - __clz(sidel + 1);    // 0..4
        const int j_m   = sidel + 1 - (1 << k_m);   // 0..2^k-1
        int* const rowU = (lane < 31) ? &TT1[k_m][0] : &TT2[k_m][0];

        int n = 0;
        for (int w = 0; w < NWIN && n < KOUT; ++w) {
            const int cb = w * TPB;
            // lane-major payloads: candidate cb + lane*8 + s  (order = (lane,s) lex)
            const ulonglong2* kp = (const ulonglong2*)&keys[cb + lane * SLOTS];
            const ulonglong2 q0 = kp[0];
            const ulonglong2 q1 = kp[1];
            const ulonglong2 q2 = kp[2];
            const ulonglong2 q3 = kp[3];
            unsigned pv[SLOTS] = { (unsigned)q0.x, (unsigned)q0.y,
                                   (unsigned)q1.x, (unsigned)q1.y,
                                   (unsigned)q2.x, (unsigned)q2.y,
                                   (unsigned)q3.x, (unsigned)q3.y };
            int cs[SLOTS], ce[SLOTS];
            #pragma unroll
            for (int s = 0; s < SLOTS; ++s) {
                ce[s] = (int)(pv[s] & 511u);
                cs[s] = (int)((pv[s] >> 9) & 511u);
            }

            // O(1) filter vs current tables:
            // crossing iff max s2e[st+1..en] > en  or  min e2s[st..en-1] < st
            unsigned alive8 = 0;
            #pragma unroll
            for (int s = 0; s < SLOTS; ++s) {
                const int wd = ce[s] - cs[s];
                bool cross = false;
                if (wd > 0) {
                    if (wd < 32) {
                        const int k   = 31 - __clz(wd);    // 0..4
                        const int off = 1 << k;
                        const int mx  = max(TT1[k][cs[s] + 1], TT1[k][ce[s] + 1 - off]);
                        const int mn  = min(TT2[k][cs[s]],     TT2[k][ce[s] - off]);
                        cross = (mx > ce[s]) || (mn < cs[s]);
                    } else {                                // cold path (wd>=32)
                        for (int j = cs[s]; j <= ce[s]; ++j)
                            cross |= ((j > cs[s]) && (TT1[0][j] > ce[s])) ||
                                     ((j < ce[s]) && (TT2[0][j] < cs[s]));
                    }
                }
                alive8 |= ((unsigned)!cross) << s;
            }

            // serial pop loop (wave-internal, no barriers)
            for (;;) {
                const unsigned long long anyb = __ballot(alive8 != 0u);
                if (anyb == 0ull) break;                    // window exhausted
                const int lwin = __ffsll((long long)anyb) - 1;
                const int sl   = __ffs((int)alive8) - 1;
                unsigned firstp = pv[0];
                #pragma unroll
                for (int s = 1; s < SLOTS; ++s) firstp = (sl == s) ? pv[s] : firstp;
                const unsigned spay = READLANE(firstp, lwin);
                const int sen = (int)(spay & 511u);
                const int sst = (int)((spay >> 9) & 511u);

                if (lane == 62) acc_list[n] = spay;
                if (lane < 31)      { const int i = sst - j_m; if (i >= 0) atomicMax(&rowU[i], sen); }
                else if (lane < 62) { const int i = sen - j_m; if (i >= 0) atomicMin(&rowU[i], sst); }
                if (lane == lwin) alive8 &= ~(1u << sl);
                ++n;
                if (n >= KOUT) break;
                #pragma unroll
                for (int s = 0; s < SLOTS; ++s) {           // branch-free retest
                    const bool c = ((cs[s] < sst) & (sst <= ce[s]) & (sen > ce[s])) |
                                   ((sst < cs[s]) & (sen >= cs[s]) & (sen < ce[s]));
                    alive8 &= ~(((unsigned)c) << s);
                }
            }
        }
        if (lane == 0) n_sh = n;
    }
    __syncthreads();                            // publish acc_list / n_sh

    // ---- final (start,end) rank-sort (parallel count) + output --------------
    const int n = n_sh;
    if (tid < KOUT) {
        unsigned p = (tid < n) ? acc_list[tid] : acc_list[0];
        paybuf[tid] = p;
        mkbuf[tid]  = ((p & 0x3FFFFu) << 7) | (unsigned)tid;   // stable tie-break
    }
    __syncthreads();
    {
        const int i = tid >> 2, q = tid & 3;
        const unsigned mk = mkbuf[i];
        int c = 0;
        #pragma unroll
        for (int x = 0; x < 32; ++x) c += (mkbuf[q * 32 + x] < mk) ? 1 : 0;
        cnt[(i << 2) | q] = c;
    }
    __syncthreads();
    if (tid < KOUT) {
        const int r = cnt[tid * 4] + cnt[tid * 4 + 1] + cnt[tid * 4 + 2] + cnt[tid * 4 + 3];
        out[sent * KOUT + r] = (int)(paybuf[tid] >> 18);
    }
}

// ---------------------------------------------------------------------------
// Fallback monolithic kernel (round-2, known-correct) if ws is too small.
// ---------------------------------------------------------------------------
__global__ __launch_bounds__(TPB) void extract_spans_mono(
    const float* __restrict__ scores,
    const int*   __restrict__ starts,
    const int*   __restrict__ ends,
    int*         __restrict__ out)
{
    __shared__ unsigned long long keys[NCAND];
    __shared__ unsigned acc_list[KOUT];
    __shared__ unsigned long long amask[TPB/64];
    __shared__ unsigned mkbuf[KOUT];
    __shared__ unsigned paybuf[KOUT];

    const int  sent = blockIdx.x;
    const int  tid  = threadIdx.x;
    const long base = (long)sent * NCAND;

    for (int i = tid; i < NCAND; i += TPB) {
        unsigned u = __float_as_uint(scores[base + i]);
        unsigned o = (u & 0x80000000u) ? ~u : (u | 0x80000000u);
        unsigned d = ~o;
        unsigned st = (unsigned)starts[base + i];
        unsigned en = (unsigned)ends[base + i];
        keys[i] = ((unsigned long long)d << 32) | ((unsigned)i << 18) | (st << 9) | en;
    }
    for (int k = 2; k <= NCAND; k <<= 1) {
        for (int j = k >> 1; j > 0; j >>= 1) {
            __syncthreads();
            for (int p = tid; p < NCAND / 2; p += TPB) {
                int low = p & (j - 1);
                int i   = ((p - low) << 1) | low;
                int q   = i | j;
                unsigned long long a = keys[i];
                unsigned long long b = keys[q];
                bool up = ((i & k) == 0);
                if ((a > b) == up) { keys[i] = b; keys[q] = a; }
            }
        }
    }
    __syncthreads();

    int  nn   = 0;
    bool done = false;
    for (int cb = 0; cb < NCAND && !done; cb += TPB) {
        const unsigned pay = (unsigned)keys[cb + tid];
        const int en = (int)(pay & 511u);
        const int st = (int)((pay >> 9) & 511u);
        bool alive = true;
        for (int a = 0; a < nn; ++a) {
            unsigned ap = acc_list[a];
            int ae = (int)(ap & 511u), as = (int)((ap >> 9) & 511u);
            if ((st < as && as <= en && ae > en) || (as < st && ae >= st && ae < en)) {
                alive = false; break;
            }
        }
        for (;;) {
            unsigned long long m = __ballot((int)alive);
            if ((tid & 63) == 0) amask[tid >> 6] = m;
            __syncthreads();
            int s = -1;
            #pragma unroll
            for (int w = 0; w < TPB / 64; ++w) {
                unsigned long long mw = amask[w];
                if (s < 0 && mw) s = (w << 6) + __ffsll((long long)mw) - 1;
            }
            __syncthreads();
            if (s < 0) break;
            unsigned spay = (unsigned)keys[cb + s];
            int sen = (int)(spay & 511u), sst = (int)((spay >> 9) & 511u);
            if (tid == 0) acc_list[nn] = spay;
            ++nn;
            if (nn == KOUT) { done = true; break; }
            if (alive) {
                alive = (tid != s) &&
                        !((st < sst && sst <= en && sen > en) ||
                          (sst < st && sen >= st && sen < en));
            }
        }
    }
    __syncthreads();
    if (tid < KOUT) {
        unsigned pay = (tid < nn) ? acc_list[tid] : acc_list[0];
        paybuf[tid] = pay;
        mkbuf[tid]  = ((pay & 0x3FFFFu) << 7) | (unsigned)tid;
    }
    __syncthreads();
    if (tid < KOUT) {
        unsigned mk = mkbuf[tid];
        int rank = 0;
        for (int t2 = 0; t2 < KOUT; ++t2)
            rank += (mkbuf[t2] < mk) ? 1 : 0;
        out[sent * KOUT + rank] = (int)(paybuf[tid] >> 18);
    }
}

extern "C" void kernel_launch(void* const* d_in, const int* in_sizes, int n_in,
                              void* d_out, int out_size, void* d_ws, size_t ws_size,
                              hipStream_t stream) {
    const float* scores = (const float*)d_in[0];
    const int*   starts = (const int*)d_in[1];
    const int*   ends   = (const int*)d_in[2];
    int*         out    = (int*)d_out;

    const size_t ws_needed = (size_t)NSENT * NCAND * sizeof(unsigned long long); // 4 MiB
    if (ws_size >= ws_needed) {
        unsigned long long* ws = (unsigned long long*)d_ws;
        sort_chunks_kernel<<<NSENT * NCHUNK, TPB, 0, stream>>>(scores, starts, ends, ws);
        merge_greedy_kernel<<<NSENT, TPB, 0, stream>>>(ws, out);
    } else {
        extract_spans_mono<<<NSENT, TPB, 0, stream>>>(scores, starts, ends, out);
    }
}

// Round 9
// 124.000 us; speedup vs baseline: 1.3106x; 1.3106x over previous
//
#include <hip/hip_runtime.h>

#define NSENT 64
#define NCAND 8192
#define LMAX  512
#define KOUT  128
#define TPB   512
#define CHUNK 1024
#define NCHUNK (NCAND / CHUNK)   // 8

#if defined(__has_builtin)
#if __has_builtin(__builtin_amdgcn_readlane)
#define READLANE(v, l) __builtin_amdgcn_readlane((unsigned)(v), (unsigned)(l))
#endif
#endif
#ifndef READLANE
#define READLANE(v, l) ((unsigned)__shfl((int)(v), (int)(l)))
#endif

// ---------------------------------------------------------------------------
// Kernel A (unchanged): 512 blocks (sentence = bid>>3, chunk = bid&7).
// Bitonic-sort 1024 u64 keys in LDS, write sorted chunk to ws.
// Key: high 32 = descending-orderable score bits, low 31 = (idx<<18)|(st<<9)|en
// ---------------------------------------------------------------------------
__global__ __launch_bounds__(TPB) void sort_chunks_kernel(
    const float* __restrict__ scores,
    const int*   __restrict__ starts,
    const int*   __restrict__ ends,
    unsigned long long* __restrict__ ws)
{
    __shared__ unsigned long long lk[CHUNK];
    const int  bid   = blockIdx.x;
    const int  sent  = bid >> 3;
    const int  chunk = bid & 7;
    const int  tid   = threadIdx.x;
    const long gbase = (long)sent * NCAND + (long)chunk * CHUNK;

    for (int i = tid; i < CHUNK; i += TPB) {
        unsigned u  = __float_as_uint(scores[gbase + i]);
        unsigned o  = (u & 0x80000000u) ? ~u : (u | 0x80000000u); // asc-orderable
        unsigned d  = ~o;                                          // descending
        unsigned st = (unsigned)starts[gbase + i];
        unsigned en = (unsigned)ends[gbase + i];
        unsigned gi = (unsigned)(chunk * CHUNK + i);               // idx in sentence
        lk[i] = ((unsigned long long)d << 32) | (gi << 18) | (st << 9) | en;
    }

    for (int k = 2; k <= CHUNK; k <<= 1) {
        for (int j = k >> 1; j > 0; j >>= 1) {
            __syncthreads();
            const int p   = tid;               // CHUNK/2 == TPB: one CX per thread
            const int low = p & (j - 1);
            const int i   = ((p - low) << 1) | low;
            const int q   = i | j;
            unsigned long long a = lk[i];
            unsigned long long b = lk[q];
            bool up = ((i & k) == 0);
            if ((a > b) == up) { lk[i] = b; lk[q] = a; }
        }
    }
    __syncthreads();

    unsigned long long* wo = ws + (long)bid * CHUNK;
    for (int i = tid; i < CHUNK; i += TPB) wo[i] = lk[i];
}

// ---------------------------------------------------------------------------
// Kernel B1: 64 blocks. Load 8 sorted runs, merge-path merge in 3 stages in
// LDS, write the fully-sorted 8192 back IN PLACE to ws (same region).
// ---------------------------------------------------------------------------
__global__ __launch_bounds__(TPB) void merge_kernel(
    unsigned long long* __restrict__ ws)
{
    __shared__ __align__(16) unsigned long long keys[NCAND];  // 64 KiB
    const int sent = blockIdx.x;
    const int tid  = threadIdx.x;
    unsigned long long* wi = ws + (long)sent * NCAND;

    {
        const ulonglong2* wi2 = (const ulonglong2*)wi;
        ulonglong2* k2 = (ulonglong2*)keys;
        for (int i = tid; i < NCAND / 2; i += TPB) k2[i] = wi2[i];
    }
    __syncthreads();

    #pragma unroll
    for (int stg = 0; stg < 3; ++stg) {
        const int Lh  = CHUNK << stg;          // 1024, 2048, 4096
        const int tpp = Lh >> 3;               // threads per pair
        const int pair = tid / tpp;
        const int o    = (tid % tpp) * 16;
        const unsigned long long* A = keys + pair * (Lh * 2);
        const unsigned long long* B = A + Lh;
        int lo = (o > Lh) ? o - Lh : 0;
        int hi = (o < Lh) ? o : Lh;
        while (lo < hi) {                      // smallest i : A[i] > B[o-1-i]
            int mid = (lo + hi) >> 1;
            if (A[mid] <= B[o - 1 - mid]) lo = mid + 1; else hi = mid;
        }
        int i = lo, j = o - lo;
        unsigned long long r[16];
        #pragma unroll
        for (int x = 0; x < 16; ++x) {
            bool ta = (j >= Lh) || (i < Lh && A[i] <= B[j]);
            r[x] = ta ? A[i++] : B[j++];
        }
        __syncthreads();                       // all reads done before overwrite
        unsigned long long* O = keys + pair * (Lh * 2) + o;
        #pragma unroll
        for (int x = 0; x < 16; ++x) O[x] = r[x];
        __syncthreads();
    }

    {
        const ulonglong2* k2 = (const ulonglong2*)keys;
        ulonglong2* wo2 = (ulonglong2*)wi;
        for (int i = tid; i < NCAND / 2; i += TPB) wo2[i] = k2[i];
    }
}

// ---------------------------------------------------------------------------
// Kernel B2: 64 blocks x 128 threads. Greedy non-crossing selection.
//  - wave 0 only: 128 windows of 64 candidates, ONE candidate per lane,
//    read directly from global ws with depth-2 prefetch (no LDS key array)
//  - O(1) sparse-table crossing filter (4 independent LDS reads)
//  - pop loop: ballot -> readlane(own pay) -> 1-candidate retest;
//    62-lane LDS-atomic incremental table update (fire-and-forget)
//  - rank-sort of the <=128 selected by (start,end) with all 128 threads
// ---------------------------------------------------------------------------
__global__ __launch_bounds__(128) void greedy_kernel(
    const unsigned long long* __restrict__ ws,
    int* __restrict__ out)
{
    // TT1[k][i] = max s2e over [i, i+2^k) ; TT2[k][i] = min e2s over [i, i+2^k)
    __shared__ int TT1[5][LMAX];              // 10 KiB
    __shared__ int TT2[5][LMAX];              // 10 KiB
    __shared__ unsigned acc_list[KOUT];
    __shared__ int      n_sh;
    __shared__ unsigned mkbuf[KOUT];
    __shared__ unsigned paybuf[KOUT];

    const int sent = blockIdx.x;
    const int tid  = threadIdx.x;
    const unsigned long long* wsp = ws + (long)sent * NCAND;

    for (int i = tid; i < 5 * LMAX; i += 128) {
        (&TT1[0][0])[i] = -1;
        (&TT2[0][0])[i] = LMAX;
    }
    __syncthreads();

    if (tid < 64) {
        const int lane = tid;
        // incremental-update role: accepted (sst,sen) bumps TT1[k][i] for
        // i in [sst-2^k+1, sst] across 5 levels = 31 cells; TT2 likewise.
        const int sidel = (lane < 31) ? lane : (lane - 31);
        const int k_m   = 31 - __clz(sidel + 1);    // 0..4
        const int j_m   = sidel + 1 - (1 << k_m);   // 0..2^k-1
        int* const rowU = (lane < 31) ? &TT1[k_m][0] : &TT2[k_m][0];

        const int NW = NCAND / 64;                  // 128 windows
        unsigned long long kv0 = wsp[lane];         // prefetch w=0
        unsigned long long kv1 = wsp[64 + lane];    // prefetch w=1
        int n = 0;

        for (int w = 0; w < NW && n < KOUT; ++w) {
            const unsigned pay = (unsigned)kv0;     // my candidate this window
            kv0 = kv1;                              // rotate prefetch pipeline
            kv1 = (w + 2 < NW) ? wsp[(long)(w + 2) * 64 + lane] : 0ull;

            const int en = (int)(pay & 511u);
            const int st = (int)((pay >> 9) & 511u);
            const int wd = en - st;

            // O(1) filter: crossing iff max s2e[st+1..en] > en
            //                        or min e2s[st..en-1] < st
            bool alive = true;
            if (wd > 0) {
                bool cross;
                if (wd < 32) {
                    const int k   = 31 - __clz(wd);       // 0..4
                    const int off = 1 << k;
                    const int mx  = max(TT1[k][st + 1], TT1[k][en + 1 - off]);
                    const int mn  = min(TT2[k][st],     TT2[k][en - off]);
                    cross = (mx > en) || (mn < st);
                } else {                                   // generic cold path
                    cross = false;
                    for (int j = st; j <= en; ++j)
                        cross |= ((j > st) && (TT1[0][j] > en)) ||
                                 ((j < en) && (TT2[0][j] < st));
                }
                alive = !cross;
            }

            // pop loop: each pop is an accept (mask kept current)
            for (;;) {
                const unsigned long long anyb = __ballot((int)alive);
                if (anyb == 0ull) break;                   // window exhausted
                const int lwin = __ffsll((long long)anyb) - 1;
                const unsigned spay = READLANE(pay, lwin); // winner's own candidate
                const int sen = (int)(spay & 511u);
                const int sst = (int)((spay >> 9) & 511u);

                if (lane == 62) acc_list[n] = spay;
                if (lane < 31)      { const int i = sst - j_m; if (i >= 0) atomicMax(&rowU[i], sen); }
                else if (lane < 62) { const int i = sen - j_m; if (i >= 0) atomicMin(&rowU[i], sst); }
                if (lane == lwin) alive = false;
                ++n;
                if (n >= KOUT) break;
                // retest my single candidate vs the new span (branch-free)
                const bool c = ((st < sst) & (sst <= en) & (sen > en)) |
                               ((sst < st) & (sen >= st) & (sen < en));
                alive = alive & !c;
            }
        }
        if (lane == 0) n_sh = n;
    }
    __syncthreads();                            // publish acc_list / n_sh

    // ---- final (start,end) rank-sort + output (128 threads, 1 output each)
    const int n = n_sh;
    {
        const unsigned p = (tid < n) ? acc_list[tid] : acc_list[0];
        paybuf[tid] = p;
        mkbuf[tid]  = ((p & 0x3FFFFu) << 7) | (unsigned)tid;   // stable tie-break
    }
    __syncthreads();
    {
        const unsigned mk = mkbuf[tid];
        int r = 0;
        #pragma unroll 8
        for (int t2 = 0; t2 < KOUT; ++t2) r += (mkbuf[t2] < mk) ? 1 : 0;
        out[sent * KOUT + r] = (int)(paybuf[tid] >> 18);
    }
}

// ---------------------------------------------------------------------------
// Fallback monolithic kernel (round-2, known-correct) if ws is too small.
// ---------------------------------------------------------------------------
__global__ __launch_bounds__(TPB) void extract_spans_mono(
    const float* __restrict__ scores,
    const int*   __restrict__ starts,
    const int*   __restrict__ ends,
    int*         __restrict__ out)
{
    __shared__ unsigned long long keys[NCAND];
    __shared__ unsigned acc_list[KOUT];
    __shared__ unsigned long long amask[TPB/64];
    __shared__ unsigned mkbuf[KOUT];
    __shared__ unsigned paybuf[KOUT];

    const int  sent = blockIdx.x;
    const int  tid  = threadIdx.x;
    const long base = (long)sent * NCAND;

    for (int i = tid; i < NCAND; i += TPB) {
        unsigned u = __float_as_uint(scores[base + i]);
        unsigned o = (u & 0x80000000u) ? ~u : (u | 0x80000000u);
        unsigned d = ~o;
        unsigned st = (unsigned)starts[base + i];
        unsigned en = (unsigned)ends[base + i];
        keys[i] = ((unsigned long long)d << 32) | ((unsigned)i << 18) | (st << 9) | en;
    }
    for (int k = 2; k <= NCAND; k <<= 1) {
        for (int j = k >> 1; j > 0; j >>= 1) {
            __syncthreads();
            for (int p = tid; p < NCAND / 2; p += TPB) {
                int low = p & (j - 1);
                int i   = ((p - low) << 1) | low;
                int q   = i | j;
                unsigned long long a = keys[i];
                unsigned long long b = keys[q];
                bool up = ((i & k) == 0);
                if ((a > b) == up) { keys[i] = b; keys[q] = a; }
            }
        }
    }
    __syncthreads();

    int  nn   = 0;
    bool done = false;
    for (int cb = 0; cb < NCAND && !done; cb += TPB) {
        const unsigned pay = (unsigned)keys[cb + tid];
        const int en = (int)(pay & 511u);
        const int st = (int)((pay >> 9) & 511u);
        bool alive = true;
        for (int a = 0; a < nn; ++a) {
            unsigned ap = acc_list[a];
            int ae = (int)(ap & 511u), as = (int)((ap >> 9) & 511u);
            if ((st < as && as <= en && ae > en) || (as < st && ae >= st && ae < en)) {
                alive = false; break;
            }
        }
        for (;;) {
            unsigned long long m = __ballot((int)alive);
            if ((tid & 63) == 0) amask[tid >> 6] = m;
            __syncthreads();
            int s = -1;
            #pragma unroll
            for (int w = 0; w < TPB / 64; ++w) {
                unsigned long long mw = amask[w];
                if (s < 0 && mw) s = (w << 6) + __ffsll((long long)mw) - 1;
            }
            __syncthreads();
            if (s < 0) break;
            unsigned spay = (unsigned)keys[cb + s];
            int sen = (int)(spay & 511u), sst = (int)((spay >> 9) & 511u);
            if (tid == 0) acc_list[nn] = spay;
            ++nn;
            if (nn == KOUT) { done = true; break; }
            if (alive) {
                alive = (tid != s) &&
                        !((st < sst && sst <= en && sen > en) ||
                          (sst < st && sen >= st && sen < en));
            }
        }
    }
    __syncthreads();
    if (tid < KOUT) {
        unsigned pay = (tid < nn) ? acc_list[tid] : acc_list[0];
        paybuf[tid] = pay;
        mkbuf[tid]  = ((pay & 0x3FFFFu) << 7) | (unsigned)tid;
    }
    __syncthreads();
    if (tid < KOUT) {
        unsigned mk = mkbuf[tid];
        int rank = 0;
        for (int t2 = 0; t2 < KOUT; ++t2)
            rank += (mkbuf[t2] < mk) ? 1 : 0;
        out[sent * KOUT + rank] = (int)(paybuf[tid] >> 18);
    }
}

extern "C" void kernel_launch(void* const* d_in, const int* in_sizes, int n_in,
                              void* d_out, int out_size, void* d_ws, size_t ws_size,
                              hipStream_t stream) {
    const float* scores = (const float*)d_in[0];
    const int*   starts = (const int*)d_in[1];
    const int*   ends   = (const int*)d_in[2];
    int*         out    = (int*)d_out;

    const size_t ws_needed = (size_t)NSENT * NCAND * sizeof(unsigned long long); // 4 MiB
    if (ws_size >= ws_needed) {
        unsigned long long* ws = (unsigned long long*)d_ws;
        sort_chunks_kernel<<<NSENT * NCHUNK, TPB, 0, stream>>>(scores, starts, ends, ws);
        merge_kernel<<<NSENT, TPB, 0, stream>>>(ws);
        greedy_kernel<<<NSENT, 128, 0, stream>>>(ws, out);
    } else {
        extract_spans_mono<<<NSENT, TPB, 0, stream>>>(scores, starts, ends, out);
    }
}